// Round 1
// baseline (303.662 us; speedup 1.0000x reference)
//
#include <hip/hip_runtime.h>
#include <cmath>

namespace {
constexpr int kN = 262144;
constexpr int kL = 16;
constexpr int kT = 1 << 19;          // hash table entries per level (power of 2!)
constexpr unsigned kTMask = kT - 1;

struct Scales { float s[kL]; };

__global__ __launch_bounds__(256) void ngp_fused(
    const float* __restrict__ pos,
    const float* __restrict__ dir,
    const float2* __restrict__ table,
    const float* __restrict__ w1, const float* __restrict__ b1,
    const float* __restrict__ w2, const float* __restrict__ b2,
    const float* __restrict__ w3, const float* __restrict__ b3,
    const float* __restrict__ w4, const float* __restrict__ b4,
    const float* __restrict__ w5, const float* __restrict__ b5,
    float* __restrict__ out, Scales sc)
{
    const int i = blockIdx.x * blockDim.x + threadIdx.x;

    // position -> [0,1]   (SB = 1)
    const float px = (pos[i * 3 + 0] + 1.0f) * 0.5f;
    const float py = (pos[i * 3 + 1] + 1.0f) * 0.5f;
    const float pz = (pos[i * 3 + 2] + 1.0f) * 0.5f;

    // ---------------- hash-grid encoding ----------------
    float enc[2 * kL];
    #pragma unroll
    for (int l = 0; l < kL; ++l) {
        const float s = sc.s[l];
        const float sx = px * s, sy = py * s, sz = pz * s;
        const float fx = floorf(sx), fy = floorf(sy), fz = floorf(sz);
        const float rx = sx - fx, ry = sy - fy, rz = sz - fz;
        const unsigned cx = (unsigned)fx, cy = (unsigned)fy, cz = (unsigned)fz;
        // only 2 distinct hashed values per dim -> hoist
        const unsigned hy0 = cy * 2654435761u, hy1 = (cy + 1u) * 2654435761u;
        const unsigned hz0 = cz * 805459861u,  hz1 = (cz + 1u) * 805459861u;
        const float2* __restrict__ tl = table + (size_t)l * kT;
        float f0 = 0.f, f1 = 0.f;
        #pragma unroll
        for (int c = 0; c < 8; ++c) {
            const unsigned ox = (c >> 2) & 1u, oy = (c >> 1) & 1u, oz = c & 1u;
            const unsigned h = (cx + ox) ^ (oy ? hy1 : hy0) ^ (oz ? hz1 : hz0);
            const float2 f = tl[h & kTMask];
            const float w = (ox ? rx : 1.f - rx) * (oy ? ry : 1.f - ry) * (oz ? rz : 1.f - rz);
            f0 = fmaf(f.x, w, f0);
            f1 = fmaf(f.y, w, f1);
        }
        enc[2 * l]     = f0;
        enc[2 * l + 1] = f1;
    }

    // ---------------- density MLP: 32 -> 64 (relu) -> 16 ----------------
    float h1[64];
    #pragma unroll
    for (int j = 0; j < 64; ++j) h1[j] = b1[j];
    #pragma unroll
    for (int k = 0; k < 32; ++k) {
        const float x = enc[k];
        #pragma unroll
        for (int j = 0; j < 64; ++j) h1[j] = fmaf(x, w1[k * 64 + j], h1[j]);
    }
    #pragma unroll
    for (int j = 0; j < 64; ++j) h1[j] = fmaxf(h1[j], 0.f);

    float h2[16];
    #pragma unroll
    for (int j = 0; j < 16; ++j) h2[j] = b2[j];
    #pragma unroll
    for (int k = 0; k < 64; ++k) {
        const float x = h1[k];
        #pragma unroll
        for (int j = 0; j < 16; ++j) h2[j] = fmaf(x, w2[k * 16 + j], h2[j]);
    }
    const float density = expf(h2[0]);

    // ---------------- SH-16 on direction ----------------
    float cin[32];
    #pragma unroll
    for (int j = 0; j < 16; ++j) cin[j] = h2[j];
    {
        const float x = dir[i * 3 + 0], y = dir[i * 3 + 1], z = dir[i * 3 + 2];
        const float xx = x * x, yy = y * y, zz = z * z;
        const float xy = x * y, yz = y * z, xz = x * z;
        cin[16] = 0.28209479177387814f;
        cin[17] = -0.48860251190291987f * y;
        cin[18] = 0.48860251190291987f * z;
        cin[19] = -0.48860251190291987f * x;
        cin[20] = 1.0925484305920792f * xy;
        cin[21] = -1.0925484305920792f * yz;
        cin[22] = 0.94617469575755997f * zz - 0.31539156525252005f;
        cin[23] = -1.0925484305920792f * xz;
        cin[24] = 0.54627421529603959f * (xx - yy);
        cin[25] = 0.59004358992664352f * y * (-3.0f * xx + yy);
        cin[26] = 2.8906114426405538f * xy * z;
        cin[27] = 0.45704579946446572f * y * (1.0f - 5.0f * zz);
        cin[28] = 0.3731763325901154f * z * (5.0f * zz - 3.0f);
        cin[29] = 0.45704579946446572f * x * (1.0f - 5.0f * zz);
        cin[30] = 1.445305721320277f * z * (xx - yy);
        cin[31] = 0.59004358992664352f * x * (xx - 3.0f * yy);
    }

    // ---------------- color MLP: 32 -> 64 (relu) -> 64 (relu) -> 3 ----------------
    float c1[64];
    #pragma unroll
    for (int j = 0; j < 64; ++j) c1[j] = b3[j];
    #pragma unroll
    for (int k = 0; k < 32; ++k) {
        const float x = cin[k];
        #pragma unroll
        for (int j = 0; j < 64; ++j) c1[j] = fmaf(x, w3[k * 64 + j], c1[j]);
    }
    #pragma unroll
    for (int j = 0; j < 64; ++j) c1[j] = fmaxf(c1[j], 0.f);

    float c2[64];
    #pragma unroll
    for (int j = 0; j < 64; ++j) c2[j] = b4[j];
    #pragma unroll
    for (int k = 0; k < 64; ++k) {
        const float x = c1[k];
        #pragma unroll
        for (int j = 0; j < 64; ++j) c2[j] = fmaf(x, w4[k * 64 + j], c2[j]);
    }
    #pragma unroll
    for (int j = 0; j < 64; ++j) c2[j] = fmaxf(c2[j], 0.f);

    float o0 = b5[0], o1 = b5[1], o2 = b5[2];
    #pragma unroll
    for (int k = 0; k < 64; ++k) {
        const float x = c2[k];
        o0 = fmaf(x, w5[k * 3 + 0], o0);
        o1 = fmaf(x, w5[k * 3 + 1], o1);
        o2 = fmaf(x, w5[k * 3 + 2], o2);
    }

    float4 res;
    res.x = density;
    res.y = 1.0f / (1.0f + expf(-o0));
    res.z = 1.0f / (1.0f + expf(-o1));
    res.w = 1.0f / (1.0f + expf(-o2));
    reinterpret_cast<float4*>(out)[i] = res;
}

} // namespace

extern "C" void kernel_launch(void* const* d_in, const int* in_sizes, int n_in,
                              void* d_out, int out_size, void* d_ws, size_t ws_size,
                              hipStream_t stream) {
    (void)in_sizes; (void)n_in; (void)d_ws; (void)ws_size; (void)out_size;

    // level scalings, computed exactly like numpy (float64 then floor)
    Scales sc;
    const double g = exp((log(2048.0) - log(16.0)) / 15.0);
    for (int l = 0; l < kL; ++l) sc.s[l] = (float)floor(16.0 * pow(g, (double)l));

    ngp_fused<<<kN / 256, 256, 0, stream>>>(
        (const float*)d_in[0],   // position
        (const float*)d_in[1],   // direction
        (const float2*)d_in[2],  // hash_table
        (const float*)d_in[3], (const float*)d_in[4],    // w1, b1
        (const float*)d_in[5], (const float*)d_in[6],    // w2, b2
        (const float*)d_in[7], (const float*)d_in[8],    // w3, b3
        (const float*)d_in[9], (const float*)d_in[10],   // w4, b4
        (const float*)d_in[11], (const float*)d_in[12],  // w5, b5
        (float*)d_out, sc);
}

// Round 2
// 301.854 us; speedup vs baseline: 1.0060x; 1.0060x over previous
//
#include <hip/hip_runtime.h>
#include <cmath>

namespace {
constexpr int kN = 262144;           // samples (2^18)
constexpr int kL = 16;               // levels
constexpr int kT = 1 << 19;          // hash entries per level (power of 2)
constexpr unsigned kTMask = kT - 1;

struct Scales { float s[kL]; };

// ---------------------------------------------------------------------------
// Kernel 1: hash-grid encode, one thread per (sample, level).
// Grid layout: blockIdx [0, kL*1024): level = blockIdx >> 10 (block-uniform),
// sample n = low bits. Output level-major: enc[l*kN + n] (coalesced).
// ---------------------------------------------------------------------------
__global__ __launch_bounds__(256) void ngp_encode(
    const float* __restrict__ pos,
    const float2* __restrict__ table,
    float2* __restrict__ enc,
    Scales sc)
{
    const int l = blockIdx.x >> 10;                       // block-uniform
    const int n = ((blockIdx.x & 1023) << 8) | threadIdx.x;

    const float s = sc.s[l];
    const float px = (pos[n * 3 + 0] + 1.0f) * 0.5f;
    const float py = (pos[n * 3 + 1] + 1.0f) * 0.5f;
    const float pz = (pos[n * 3 + 2] + 1.0f) * 0.5f;

    const float sx = px * s, sy = py * s, sz = pz * s;
    const float fx = floorf(sx), fy = floorf(sy), fz = floorf(sz);
    const float rx = sx - fx, ry = sy - fy, rz = sz - fz;
    const unsigned cx = (unsigned)fx, cy = (unsigned)fy, cz = (unsigned)fz;

    const unsigned hy0 = cy * 2654435761u, hy1 = (cy + 1u) * 2654435761u;
    const unsigned hz0 = cz * 805459861u,  hz1 = (cz + 1u) * 805459861u;
    const float2* __restrict__ tl = table + (size_t)l * kT;

    // issue all 8 gathers before consuming any
    float2 f[8];
    #pragma unroll
    for (int c = 0; c < 8; ++c) {
        const unsigned ox = (c >> 2) & 1u, oy = (c >> 1) & 1u, oz = c & 1u;
        const unsigned h = (cx + ox) ^ (oy ? hy1 : hy0) ^ (oz ? hz1 : hz0);
        f[c] = tl[h & kTMask];
    }

    float f0 = 0.f, f1 = 0.f;
    #pragma unroll
    for (int c = 0; c < 8; ++c) {
        const unsigned ox = (c >> 2) & 1u, oy = (c >> 1) & 1u, oz = c & 1u;
        const float w = (ox ? rx : 1.f - rx) * (oy ? ry : 1.f - ry) * (oz ? rz : 1.f - rz);
        f0 = fmaf(f[c].x, w, f0);
        f1 = fmaf(f[c].y, w, f1);
    }
    enc[(size_t)l * kN + n] = make_float2(f0, f1);
}

// ---------------------------------------------------------------------------
// Kernel 2: MLPs, one thread per sample. Reads enc level-major (coalesced).
// ---------------------------------------------------------------------------
__global__ __launch_bounds__(256) void ngp_mlp(
    const float2* __restrict__ enc,
    const float* __restrict__ dir,
    const float* __restrict__ w1, const float* __restrict__ b1,
    const float* __restrict__ w2, const float* __restrict__ b2,
    const float* __restrict__ w3, const float* __restrict__ b3,
    const float* __restrict__ w4, const float* __restrict__ b4,
    const float* __restrict__ w5, const float* __restrict__ b5,
    float* __restrict__ out)
{
    const int i = blockIdx.x * blockDim.x + threadIdx.x;

    float e[32];
    #pragma unroll
    for (int l = 0; l < kL; ++l) {
        const float2 v = enc[(size_t)l * kN + i];
        e[2 * l]     = v.x;
        e[2 * l + 1] = v.y;
    }

    // density MLP: 32 -> 64 (relu) -> 16
    float h1[64];
    #pragma unroll
    for (int j = 0; j < 64; ++j) h1[j] = b1[j];
    #pragma unroll
    for (int k = 0; k < 32; ++k) {
        const float x = e[k];
        #pragma unroll
        for (int j = 0; j < 64; ++j) h1[j] = fmaf(x, w1[k * 64 + j], h1[j]);
    }
    #pragma unroll
    for (int j = 0; j < 64; ++j) h1[j] = fmaxf(h1[j], 0.f);

    float h2[16];
    #pragma unroll
    for (int j = 0; j < 16; ++j) h2[j] = b2[j];
    #pragma unroll
    for (int k = 0; k < 64; ++k) {
        const float x = h1[k];
        #pragma unroll
        for (int j = 0; j < 16; ++j) h2[j] = fmaf(x, w2[k * 16 + j], h2[j]);
    }
    const float density = expf(h2[0]);

    // SH-16
    float cin[32];
    #pragma unroll
    for (int j = 0; j < 16; ++j) cin[j] = h2[j];
    {
        const float x = dir[i * 3 + 0], y = dir[i * 3 + 1], z = dir[i * 3 + 2];
        const float xx = x * x, yy = y * y, zz = z * z;
        const float xy = x * y, yz = y * z, xz = x * z;
        cin[16] = 0.28209479177387814f;
        cin[17] = -0.48860251190291987f * y;
        cin[18] = 0.48860251190291987f * z;
        cin[19] = -0.48860251190291987f * x;
        cin[20] = 1.0925484305920792f * xy;
        cin[21] = -1.0925484305920792f * yz;
        cin[22] = 0.94617469575755997f * zz - 0.31539156525252005f;
        cin[23] = -1.0925484305920792f * xz;
        cin[24] = 0.54627421529603959f * (xx - yy);
        cin[25] = 0.59004358992664352f * y * (-3.0f * xx + yy);
        cin[26] = 2.8906114426405538f * xy * z;
        cin[27] = 0.45704579946446572f * y * (1.0f - 5.0f * zz);
        cin[28] = 0.3731763325901154f * z * (5.0f * zz - 3.0f);
        cin[29] = 0.45704579946446572f * x * (1.0f - 5.0f * zz);
        cin[30] = 1.445305721320277f * z * (xx - yy);
        cin[31] = 0.59004358992664352f * x * (xx - 3.0f * yy);
    }

    // color MLP: 32 -> 64 (relu) -> 64 (relu) -> 3
    float c1[64];
    #pragma unroll
    for (int j = 0; j < 64; ++j) c1[j] = b3[j];
    #pragma unroll
    for (int k = 0; k < 32; ++k) {
        const float x = cin[k];
        #pragma unroll
        for (int j = 0; j < 64; ++j) c1[j] = fmaf(x, w3[k * 64 + j], c1[j]);
    }
    #pragma unroll
    for (int j = 0; j < 64; ++j) c1[j] = fmaxf(c1[j], 0.f);

    float c2[64];
    #pragma unroll
    for (int j = 0; j < 64; ++j) c2[j] = b4[j];
    #pragma unroll
    for (int k = 0; k < 64; ++k) {
        const float x = c1[k];
        #pragma unroll
        for (int j = 0; j < 64; ++j) c2[j] = fmaf(x, w4[k * 64 + j], c2[j]);
    }
    #pragma unroll
    for (int j = 0; j < 64; ++j) c2[j] = fmaxf(c2[j], 0.f);

    float o0 = b5[0], o1 = b5[1], o2 = b5[2];
    #pragma unroll
    for (int k = 0; k < 64; ++k) {
        const float x = c2[k];
        o0 = fmaf(x, w5[k * 3 + 0], o0);
        o1 = fmaf(x, w5[k * 3 + 1], o1);
        o2 = fmaf(x, w5[k * 3 + 2], o2);
    }

    float4 res;
    res.x = density;
    res.y = 1.0f / (1.0f + expf(-o0));
    res.z = 1.0f / (1.0f + expf(-o1));
    res.w = 1.0f / (1.0f + expf(-o2));
    reinterpret_cast<float4*>(out)[i] = res;
}

// ---------------------------------------------------------------------------
// Fallback: fully fused single kernel (round-1 version), used if ws too small.
// ---------------------------------------------------------------------------
__global__ __launch_bounds__(256) void ngp_fused(
    const float* __restrict__ pos,
    const float* __restrict__ dir,
    const float2* __restrict__ table,
    const float* __restrict__ w1, const float* __restrict__ b1,
    const float* __restrict__ w2, const float* __restrict__ b2,
    const float* __restrict__ w3, const float* __restrict__ b3,
    const float* __restrict__ w4, const float* __restrict__ b4,
    const float* __restrict__ w5, const float* __restrict__ b5,
    float* __restrict__ out, Scales sc)
{
    const int i = blockIdx.x * blockDim.x + threadIdx.x;
    const float px = (pos[i * 3 + 0] + 1.0f) * 0.5f;
    const float py = (pos[i * 3 + 1] + 1.0f) * 0.5f;
    const float pz = (pos[i * 3 + 2] + 1.0f) * 0.5f;

    float e[32];
    #pragma unroll
    for (int l = 0; l < kL; ++l) {
        const float s = sc.s[l];
        const float sx = px * s, sy = py * s, sz = pz * s;
        const float fx = floorf(sx), fy = floorf(sy), fz = floorf(sz);
        const float rx = sx - fx, ry = sy - fy, rz = sz - fz;
        const unsigned cx = (unsigned)fx, cy = (unsigned)fy, cz = (unsigned)fz;
        const unsigned hy0 = cy * 2654435761u, hy1 = (cy + 1u) * 2654435761u;
        const unsigned hz0 = cz * 805459861u,  hz1 = (cz + 1u) * 805459861u;
        const float2* __restrict__ tl = table + (size_t)l * kT;
        float f0 = 0.f, f1 = 0.f;
        #pragma unroll
        for (int c = 0; c < 8; ++c) {
            const unsigned ox = (c >> 2) & 1u, oy = (c >> 1) & 1u, oz = c & 1u;
            const unsigned h = (cx + ox) ^ (oy ? hy1 : hy0) ^ (oz ? hz1 : hz0);
            const float2 f = tl[h & kTMask];
            const float w = (ox ? rx : 1.f - rx) * (oy ? ry : 1.f - ry) * (oz ? rz : 1.f - rz);
            f0 = fmaf(f.x, w, f0);
            f1 = fmaf(f.y, w, f1);
        }
        e[2 * l] = f0; e[2 * l + 1] = f1;
    }

    float h1[64];
    #pragma unroll
    for (int j = 0; j < 64; ++j) h1[j] = b1[j];
    #pragma unroll
    for (int k = 0; k < 32; ++k) {
        const float x = e[k];
        #pragma unroll
        for (int j = 0; j < 64; ++j) h1[j] = fmaf(x, w1[k * 64 + j], h1[j]);
    }
    #pragma unroll
    for (int j = 0; j < 64; ++j) h1[j] = fmaxf(h1[j], 0.f);

    float h2[16];
    #pragma unroll
    for (int j = 0; j < 16; ++j) h2[j] = b2[j];
    #pragma unroll
    for (int k = 0; k < 64; ++k) {
        const float x = h1[k];
        #pragma unroll
        for (int j = 0; j < 16; ++j) h2[j] = fmaf(x, w2[k * 16 + j], h2[j]);
    }
    const float density = expf(h2[0]);

    float cin[32];
    #pragma unroll
    for (int j = 0; j < 16; ++j) cin[j] = h2[j];
    {
        const float x = dir[i * 3 + 0], y = dir[i * 3 + 1], z = dir[i * 3 + 2];
        const float xx = x * x, yy = y * y, zz = z * z;
        const float xy = x * y, yz = y * z, xz = x * z;
        cin[16] = 0.28209479177387814f;
        cin[17] = -0.48860251190291987f * y;
        cin[18] = 0.48860251190291987f * z;
        cin[19] = -0.48860251190291987f * x;
        cin[20] = 1.0925484305920792f * xy;
        cin[21] = -1.0925484305920792f * yz;
        cin[22] = 0.94617469575755997f * zz - 0.31539156525252005f;
        cin[23] = -1.0925484305920792f * xz;
        cin[24] = 0.54627421529603959f * (xx - yy);
        cin[25] = 0.59004358992664352f * y * (-3.0f * xx + yy);
        cin[26] = 2.8906114426405538f * xy * z;
        cin[27] = 0.45704579946446572f * y * (1.0f - 5.0f * zz);
        cin[28] = 0.3731763325901154f * z * (5.0f * zz - 3.0f);
        cin[29] = 0.45704579946446572f * x * (1.0f - 5.0f * zz);
        cin[30] = 1.445305721320277f * z * (xx - yy);
        cin[31] = 0.59004358992664352f * x * (xx - 3.0f * yy);
    }

    float c1[64];
    #pragma unroll
    for (int j = 0; j < 64; ++j) c1[j] = b3[j];
    #pragma unroll
    for (int k = 0; k < 32; ++k) {
        const float x = cin[k];
        #pragma unroll
        for (int j = 0; j < 64; ++j) c1[j] = fmaf(x, w3[k * 64 + j], c1[j]);
    }
    #pragma unroll
    for (int j = 0; j < 64; ++j) c1[j] = fmaxf(c1[j], 0.f);

    float c2[64];
    #pragma unroll
    for (int j = 0; j < 64; ++j) c2[j] = b4[j];
    #pragma unroll
    for (int k = 0; k < 64; ++k) {
        const float x = c1[k];
        #pragma unroll
        for (int j = 0; j < 64; ++j) c2[j] = fmaf(x, w4[k * 64 + j], c2[j]);
    }
    #pragma unroll
    for (int j = 0; j < 64; ++j) c2[j] = fmaxf(c2[j], 0.f);

    float o0 = b5[0], o1 = b5[1], o2 = b5[2];
    #pragma unroll
    for (int k = 0; k < 64; ++k) {
        const float x = c2[k];
        o0 = fmaf(x, w5[k * 3 + 0], o0);
        o1 = fmaf(x, w5[k * 3 + 1], o1);
        o2 = fmaf(x, w5[k * 3 + 2], o2);
    }

    float4 res;
    res.x = density;
    res.y = 1.0f / (1.0f + expf(-o0));
    res.z = 1.0f / (1.0f + expf(-o1));
    res.w = 1.0f / (1.0f + expf(-o2));
    reinterpret_cast<float4*>(out)[i] = res;
}

} // namespace

extern "C" void kernel_launch(void* const* d_in, const int* in_sizes, int n_in,
                              void* d_out, int out_size, void* d_ws, size_t ws_size,
                              hipStream_t stream) {
    (void)in_sizes; (void)n_in; (void)out_size;

    Scales sc;
    const double g = exp((log(2048.0) - log(16.0)) / 15.0);
    for (int l = 0; l < kL; ++l) sc.s[l] = (float)floor(16.0 * pow(g, (double)l));

    const float*  pos   = (const float*)d_in[0];
    const float*  dir   = (const float*)d_in[1];
    const float2* table = (const float2*)d_in[2];
    const float *w1 = (const float*)d_in[3],  *b1 = (const float*)d_in[4];
    const float *w2 = (const float*)d_in[5],  *b2 = (const float*)d_in[6];
    const float *w3 = (const float*)d_in[7],  *b3 = (const float*)d_in[8];
    const float *w4 = (const float*)d_in[9],  *b4 = (const float*)d_in[10];
    const float *w5 = (const float*)d_in[11], *b5 = (const float*)d_in[12];
    float* out = (float*)d_out;

    const size_t enc_bytes = (size_t)kL * kN * sizeof(float2);  // 33.6 MB
    if (ws_size >= enc_bytes) {
        float2* enc = (float2*)d_ws;
        ngp_encode<<<kL * 1024, 256, 0, stream>>>(pos, table, enc, sc);
        ngp_mlp<<<kN / 256, 256, 0, stream>>>(enc, dir,
            w1, b1, w2, b2, w3, b3, w4, b4, w5, b5, out);
    } else {
        ngp_fused<<<kN / 256, 256, 0, stream>>>(pos, dir, table,
            w1, b1, w2, b2, w3, b3, w4, b4, w5, b5, out, sc);
    }
}

// Round 3
// 166.302 us; speedup vs baseline: 1.8260x; 1.8151x over previous
//
#include <hip/hip_runtime.h>
#include <cmath>

namespace {
constexpr int kN = 262144;           // samples (2^18)
constexpr int kL = 16;               // levels
constexpr int kT = 1 << 19;          // hash entries per level (power of 2)
constexpr unsigned kTMask = kT - 1;

typedef __attribute__((ext_vector_type(8))) short short8;      // 8 bf16 (A/B frag)
typedef __attribute__((ext_vector_type(4))) float f32x4;       // C/D frag
typedef __attribute__((ext_vector_type(4))) unsigned short ushort4v;

struct Scales { float s[kL]; };

__device__ __forceinline__ unsigned short f2bf(float f) {
    unsigned u = __builtin_bit_cast(unsigned, f);
    return (unsigned short)((u + 0x7FFFu + ((u >> 16) & 1u)) >> 16);  // RNE
}

// ---------------------------------------------------------------------------
// Kernel 0: pre-swizzle MLP weights into per-lane MFMA B-fragment order, bf16.
// Frag f, lane l, elem e at ushort index f*512 + l*8 + e.
// Frags: 0-3 w1[nt], 4-5 w2[q], 6-9 w3[nt], 10-17 w4[q*4+nt], 18-19 w5[q].
// B layout (16x16x32): lane l holds col=l&15, k=(l>>4)*8+e.
// ---------------------------------------------------------------------------
__global__ __launch_bounds__(256) void prep_w(
    const float* __restrict__ w1, const float* __restrict__ w2,
    const float* __restrict__ w3, const float* __restrict__ w4,
    const float* __restrict__ w5, unsigned short* __restrict__ out)
{
    const int i = blockIdx.x * 256 + threadIdx.x;   // 0..10239
    const int f = i >> 9;
    const int l = (i >> 3) & 63;
    const int e = i & 7;
    const int cl = l & 15;
    const int kg = l >> 4;
    float v = 0.0f;
    if (f < 4) {                 // w1: [32][64]
        v = w1[(kg * 8 + e) * 64 + f * 16 + cl];
    } else if (f < 6) {          // w2: [64][16]
        const int q = f - 4;
        v = w2[(q * 32 + kg * 8 + e) * 16 + cl];
    } else if (f < 10) {         // w3: [32][64]
        v = w3[(kg * 8 + e) * 64 + (f - 6) * 16 + cl];
    } else if (f < 18) {         // w4: [64][64]
        const int g = f - 10, q = g >> 2, nt = g & 3;
        v = w4[(q * 32 + kg * 8 + e) * 64 + nt * 16 + cl];
    } else {                     // w5: [64][3] padded to 16 cols
        const int q = f - 18;
        v = (cl < 3) ? w5[(q * 32 + kg * 8 + e) * 3 + cl] : 0.0f;
    }
    out[i] = f2bf(v);
}

// ---------------------------------------------------------------------------
// Kernel 1: hash-grid encode, one thread per (sample, level).
// Output packed bf16x2 (lo=feat0, hi=feat1), level-major enc[l*kN + n].
// ---------------------------------------------------------------------------
__global__ __launch_bounds__(256) void ngp_encode(
    const float* __restrict__ pos,
    const float2* __restrict__ table,
    unsigned* __restrict__ enc,
    Scales sc)
{
    const int l = blockIdx.x >> 10;                       // block-uniform
    const int n = ((blockIdx.x & 1023) << 8) | threadIdx.x;

    const float s = sc.s[l];
    const float px = (pos[n * 3 + 0] + 1.0f) * 0.5f;
    const float py = (pos[n * 3 + 1] + 1.0f) * 0.5f;
    const float pz = (pos[n * 3 + 2] + 1.0f) * 0.5f;

    const float sx = px * s, sy = py * s, sz = pz * s;
    const float fx = floorf(sx), fy = floorf(sy), fz = floorf(sz);
    const float rx = sx - fx, ry = sy - fy, rz = sz - fz;
    const unsigned cx = (unsigned)fx, cy = (unsigned)fy, cz = (unsigned)fz;

    const unsigned hy0 = cy * 2654435761u, hy1 = (cy + 1u) * 2654435761u;
    const unsigned hz0 = cz * 805459861u,  hz1 = (cz + 1u) * 805459861u;
    const float2* __restrict__ tl = table + (size_t)l * kT;

    float2 f[8];
    #pragma unroll
    for (int c = 0; c < 8; ++c) {
        const unsigned ox = (c >> 2) & 1u, oy = (c >> 1) & 1u, oz = c & 1u;
        const unsigned h = (cx + ox) ^ (oy ? hy1 : hy0) ^ (oz ? hz1 : hz0);
        f[c] = tl[h & kTMask];
    }
    float f0 = 0.f, f1 = 0.f;
    #pragma unroll
    for (int c = 0; c < 8; ++c) {
        const unsigned ox = (c >> 2) & 1u, oy = (c >> 1) & 1u, oz = c & 1u;
        const float w = (ox ? rx : 1.f - rx) * (oy ? ry : 1.f - ry) * (oz ? rz : 1.f - rz);
        f0 = fmaf(f[c].x, w, f0);
        f1 = fmaf(f[c].y, w, f1);
    }
    enc[(size_t)l * kN + n] = (unsigned)f2bf(f0) | ((unsigned)f2bf(f1) << 16);
}

// ---------------------------------------------------------------------------
// Kernel 2: fully-fused MLP via MFMA. 4 waves/block, 64 samples/wave,
// wave-private LDS (no __syncthreads). bf16 in, fp32 accumulate.
// LDS activation layout per wave: elem(k, s) at (s>>4)*1024 + k*16 + (s&15)
// (bufA, k<64) / (s>>4)*512 + k*16 + (s&15) (bufB, k<32).
// C-frag (m,nt): lane l holds col=nt*16+(l&15), rows m*16+(l>>4)*4+r.
// A-frag (m):    lane l holds row m*16+(l&15), k=(l>>4)*8+e.
// ---------------------------------------------------------------------------
__global__ __launch_bounds__(256) void ngp_mlp_mfma(
    const unsigned* __restrict__ enc,
    const unsigned short* __restrict__ wbf,
    const float* __restrict__ dir,
    const float* __restrict__ b1, const float* __restrict__ b2,
    const float* __restrict__ b3, const float* __restrict__ b4,
    const float* __restrict__ b5,
    float* __restrict__ out)
{
    __shared__ unsigned short sA[4][4096];   // 64k x 64s per wave
    __shared__ unsigned short sB[4][2048];   // 32k x 64s per wave

    const int tid = threadIdx.x;
    const int wid = tid >> 6;
    const int l   = tid & 63;
    const int cl  = l & 15;
    const int kg  = l >> 4;
    unsigned short* __restrict__ A_ = sA[wid];
    unsigned short* __restrict__ B_ = sB[wid];
    const int gbase = blockIdx.x * 256 + wid * 64;

    // ---- SH-16 for this lane's own sample, written to bufB k=16..31 ----
    {
        const int s = gbase + l;
        const float x = dir[s * 3 + 0], y = dir[s * 3 + 1], z = dir[s * 3 + 2];
        const float xx = x * x, yy = y * y, zz = z * z;
        const float xy = x * y, yz = y * z, xz = x * z;
        float sh[16];
        sh[0] = 0.28209479177387814f;
        sh[1] = -0.48860251190291987f * y;
        sh[2] = 0.48860251190291987f * z;
        sh[3] = -0.48860251190291987f * x;
        sh[4] = 1.0925484305920792f * xy;
        sh[5] = -1.0925484305920792f * yz;
        sh[6] = 0.94617469575755997f * zz - 0.31539156525252005f;
        sh[7] = -1.0925484305920792f * xz;
        sh[8] = 0.54627421529603959f * (xx - yy);
        sh[9] = 0.59004358992664352f * y * (-3.0f * xx + yy);
        sh[10] = 2.8906114426405538f * xy * z;
        sh[11] = 0.45704579946446572f * y * (1.0f - 5.0f * zz);
        sh[12] = 0.3731763325901154f * z * (5.0f * zz - 3.0f);
        sh[13] = 0.45704579946446572f * x * (1.0f - 5.0f * zz);
        sh[14] = 1.445305721320277f * z * (xx - yy);
        sh[15] = 0.59004358992664352f * x * (xx - 3.0f * yy);
        #pragma unroll
        for (int j = 0; j < 16; ++j)
            B_[(l >> 4) * 512 + (16 + j) * 16 + (l & 15)] = f2bf(sh[j]);
    }

    // ---- Layer 1: enc(32) -> h1(64), relu ----
    short8 A1[4];
    #pragma unroll
    for (int m = 0; m < 4; ++m) {
        #pragma unroll
        for (int j = 0; j < 4; ++j) {
            const unsigned v = enc[(size_t)(kg * 4 + j) * kN + (gbase + m * 16 + cl)];
            A1[m][2 * j]     = (short)(v & 0xFFFFu);
            A1[m][2 * j + 1] = (short)(v >> 16);
        }
    }
    {
        short8 B1[4];
        #pragma unroll
        for (int nt = 0; nt < 4; ++nt)
            B1[nt] = *reinterpret_cast<const short8*>(&wbf[(size_t)(nt) * 512 + l * 8]);

        f32x4 acc[4][4];
        #pragma unroll
        for (int nt = 0; nt < 4; ++nt) {
            const float bv = b1[nt * 16 + cl];
            #pragma unroll
            for (int m = 0; m < 4; ++m) {
                acc[m][nt][0] = bv; acc[m][nt][1] = bv; acc[m][nt][2] = bv; acc[m][nt][3] = bv;
            }
        }
        #pragma unroll
        for (int m = 0; m < 4; ++m)
            #pragma unroll
            for (int nt = 0; nt < 4; ++nt)
                acc[m][nt] = __builtin_amdgcn_mfma_f32_16x16x32_bf16(A1[m], B1[nt], acc[m][nt], 0, 0, 0);

        #pragma unroll
        for (int m = 0; m < 4; ++m) {
            #pragma unroll
            for (int nt = 0; nt < 4; ++nt) {
                ushort4v pk;
                #pragma unroll
                for (int r = 0; r < 4; ++r) pk[r] = f2bf(fmaxf(acc[m][nt][r], 0.0f));
                *reinterpret_cast<ushort4v*>(&A_[m * 1024 + (nt * 16 + cl) * 16 + kg * 4]) = pk;
            }
        }
    }

    // ---- Layer 2: h1(64) -> h2(16), no relu; density = exp(h2[0]) ----
    {
        short8 A2[4][2];
        #pragma unroll
        for (int m = 0; m < 4; ++m)
            #pragma unroll
            for (int q = 0; q < 2; ++q)
                #pragma unroll
                for (int e = 0; e < 8; ++e)
                    A2[m][q][e] = (short)A_[m * 1024 + (q * 32 + kg * 8 + e) * 16 + cl];

        short8 B2[2];
        #pragma unroll
        for (int q = 0; q < 2; ++q)
            B2[q] = *reinterpret_cast<const short8*>(&wbf[(size_t)(4 + q) * 512 + l * 8]);

        f32x4 acc[4];
        const float bv = b2[cl];
        #pragma unroll
        for (int m = 0; m < 4; ++m) { acc[m][0] = bv; acc[m][1] = bv; acc[m][2] = bv; acc[m][3] = bv; }
        #pragma unroll
        for (int m = 0; m < 4; ++m)
            #pragma unroll
            for (int q = 0; q < 2; ++q)
                acc[m] = __builtin_amdgcn_mfma_f32_16x16x32_bf16(A2[m][q], B2[q], acc[m], 0, 0, 0);

        #pragma unroll
        for (int m = 0; m < 4; ++m) {
            if (cl == 0) {
                #pragma unroll
                for (int r = 0; r < 4; ++r)
                    out[(size_t)(gbase + m * 16 + kg * 4 + r) * 4 + 0] = expf(acc[m][r]);
            }
            ushort4v pk;
            #pragma unroll
            for (int r = 0; r < 4; ++r) pk[r] = f2bf(acc[m][r]);
            *reinterpret_cast<ushort4v*>(&B_[m * 512 + cl * 16 + kg * 4]) = pk;
        }
    }

    // ---- Layer 3: [h2|SH](32) -> c1(64), relu ----
    {
        short8 A3[4];
        #pragma unroll
        for (int m = 0; m < 4; ++m)
            #pragma unroll
            for (int e = 0; e < 8; ++e)
                A3[m][e] = (short)B_[m * 512 + (kg * 8 + e) * 16 + cl];

        short8 B3[4];
        #pragma unroll
        for (int nt = 0; nt < 4; ++nt)
            B3[nt] = *reinterpret_cast<const short8*>(&wbf[(size_t)(6 + nt) * 512 + l * 8]);

        f32x4 acc[4][4];
        #pragma unroll
        for (int nt = 0; nt < 4; ++nt) {
            const float bv = b3[nt * 16 + cl];
            #pragma unroll
            for (int m = 0; m < 4; ++m) {
                acc[m][nt][0] = bv; acc[m][nt][1] = bv; acc[m][nt][2] = bv; acc[m][nt][3] = bv;
            }
        }
        #pragma unroll
        for (int m = 0; m < 4; ++m)
            #pragma unroll
            for (int nt = 0; nt < 4; ++nt)
                acc[m][nt] = __builtin_amdgcn_mfma_f32_16x16x32_bf16(A3[m], B3[nt], acc[m][nt], 0, 0, 0);

        #pragma unroll
        for (int m = 0; m < 4; ++m) {
            #pragma unroll
            for (int nt = 0; nt < 4; ++nt) {
                ushort4v pk;
                #pragma unroll
                for (int r = 0; r < 4; ++r) pk[r] = f2bf(fmaxf(acc[m][nt][r], 0.0f));
                *reinterpret_cast<ushort4v*>(&A_[m * 1024 + (nt * 16 + cl) * 16 + kg * 4]) = pk;
            }
        }
    }

    // ---- Layer 4: c1(64) -> c2(64), relu ----
    {
        short8 A4[4][2];
        #pragma unroll
        for (int m = 0; m < 4; ++m)
            #pragma unroll
            for (int q = 0; q < 2; ++q)
                #pragma unroll
                for (int e = 0; e < 8; ++e)
                    A4[m][q][e] = (short)A_[m * 1024 + (q * 32 + kg * 8 + e) * 16 + cl];

        short8 B4[2][4];
        #pragma unroll
        for (int q = 0; q < 2; ++q)
            #pragma unroll
            for (int nt = 0; nt < 4; ++nt)
                B4[q][nt] = *reinterpret_cast<const short8*>(&wbf[(size_t)(10 + q * 4 + nt) * 512 + l * 8]);

        f32x4 acc[4][4];
        #pragma unroll
        for (int nt = 0; nt < 4; ++nt) {
            const float bv = b4[nt * 16 + cl];
            #pragma unroll
            for (int m = 0; m < 4; ++m) {
                acc[m][nt][0] = bv; acc[m][nt][1] = bv; acc[m][nt][2] = bv; acc[m][nt][3] = bv;
            }
        }
        #pragma unroll
        for (int m = 0; m < 4; ++m)
            #pragma unroll
            for (int nt = 0; nt < 4; ++nt)
                #pragma unroll
                for (int q = 0; q < 2; ++q)
                    acc[m][nt] = __builtin_amdgcn_mfma_f32_16x16x32_bf16(A4[m][q], B4[q][nt], acc[m][nt], 0, 0, 0);

        #pragma unroll
        for (int m = 0; m < 4; ++m) {
            #pragma unroll
            for (int nt = 0; nt < 4; ++nt) {
                ushort4v pk;
                #pragma unroll
                for (int r = 0; r < 4; ++r) pk[r] = f2bf(fmaxf(acc[m][nt][r], 0.0f));
                *reinterpret_cast<ushort4v*>(&A_[m * 1024 + (nt * 16 + cl) * 16 + kg * 4]) = pk;
            }
        }
    }

    // ---- Layer 5: c2(64) -> 3, sigmoid ----
    {
        short8 A5[4][2];
        #pragma unroll
        for (int m = 0; m < 4; ++m)
            #pragma unroll
            for (int q = 0; q < 2; ++q)
                #pragma unroll
                for (int e = 0; e < 8; ++e)
                    A5[m][q][e] = (short)A_[m * 1024 + (q * 32 + kg * 8 + e) * 16 + cl];

        short8 B5[2];
        #pragma unroll
        for (int q = 0; q < 2; ++q)
            B5[q] = *reinterpret_cast<const short8*>(&wbf[(size_t)(18 + q) * 512 + l * 8]);

        f32x4 acc[4];
        const float bv = (cl < 3) ? b5[cl] : 0.0f;
        #pragma unroll
        for (int m = 0; m < 4; ++m) { acc[m][0] = bv; acc[m][1] = bv; acc[m][2] = bv; acc[m][3] = bv; }
        #pragma unroll
        for (int m = 0; m < 4; ++m)
            #pragma unroll
            for (int q = 0; q < 2; ++q)
                acc[m] = __builtin_amdgcn_mfma_f32_16x16x32_bf16(A5[m][q], B5[q], acc[m], 0, 0, 0);

        if (cl < 3) {
            #pragma unroll
            for (int m = 0; m < 4; ++m)
                #pragma unroll
                for (int r = 0; r < 4; ++r)
                    out[(size_t)(gbase + m * 16 + kg * 4 + r) * 4 + 1 + cl] =
                        1.0f / (1.0f + expf(-acc[m][r]));
        }
    }
}

} // namespace

extern "C" void kernel_launch(void* const* d_in, const int* in_sizes, int n_in,
                              void* d_out, int out_size, void* d_ws, size_t ws_size,
                              hipStream_t stream) {
    (void)in_sizes; (void)n_in; (void)out_size; (void)ws_size;

    Scales sc;
    const double g = exp((log(2048.0) - log(16.0)) / 15.0);
    for (int l = 0; l < kL; ++l) sc.s[l] = (float)floor(16.0 * pow(g, (double)l));

    const float*  pos   = (const float*)d_in[0];
    const float*  dir   = (const float*)d_in[1];
    const float2* table = (const float2*)d_in[2];
    const float *w1 = (const float*)d_in[3],  *b1 = (const float*)d_in[4];
    const float *w2 = (const float*)d_in[5],  *b2 = (const float*)d_in[6];
    const float *w3 = (const float*)d_in[7],  *b3 = (const float*)d_in[8];
    const float *w4 = (const float*)d_in[9],  *b4 = (const float*)d_in[10];
    const float *w5 = (const float*)d_in[11], *b5 = (const float*)d_in[12];
    float* out = (float*)d_out;

    // ws layout: [0, 20480) bf16 weight frags; [32768, 32768 + 16*kN*4) packed enc
    unsigned short* wbf = (unsigned short*)d_ws;
    unsigned* enc = (unsigned*)((char*)d_ws + 32768);

    prep_w<<<40, 256, 0, stream>>>(w1, w2, w3, w4, w5, wbf);
    ngp_encode<<<kL * 1024, 256, 0, stream>>>(pos, table, enc, sc);
    ngp_mlp_mfma<<<kN / 256, 256, 0, stream>>>(enc, wbf, dir,
        b1, b2, b3, b4, b5, out);
}